// Round 3
// baseline (35.853 us; speedup 1.0000x reference)
//
#include <hip/hip_runtime.h>
#include <hip/hip_bf16.h>

// out[i] = exp(-0.5 * 0.54 * ((x[i,0]-mu0)^2 + (x[i,1]-mu1)^2))
// Memory-bound streaming op, zero reuse -> non-temporal load/store hints.
// Use clang native ext_vector types: __builtin_nontemporal_* rejects
// HIP_vector_type structs (float4/float2).

typedef float f32x4 __attribute__((ext_vector_type(4)));
typedef float f32x2 __attribute__((ext_vector_type(2)));

__global__ void gauss_pdf_kernel(const f32x4* __restrict__ x,
                                 const float* __restrict__ mu,
                                 f32x2* __restrict__ out,
                                 int n_pairs) {
    const float m0 = mu[0];
    const float m1 = mu[1];
    const float k = -0.5f * 0.54f;  // -0.27

    int idx = blockIdx.x * blockDim.x + threadIdx.x;
    int stride = gridDim.x * blockDim.x;
    for (int i = idx; i < n_pairs; i += stride) {
        f32x4 v = __builtin_nontemporal_load(&x[i]);  // rows 2i,2i+1
        float d0 = v.x - m0;
        float d1 = v.y - m1;
        float d2 = v.z - m0;
        float d3 = v.w - m1;
        float q0 = (d0 * d0 + d1 * d1) * k;
        float q1 = (d2 * d2 + d3 * d3) * k;
        f32x2 r;
        r.x = __expf(q0);
        r.y = __expf(q1);
        __builtin_nontemporal_store(r, &out[i]);
    }
}

extern "C" void kernel_launch(void* const* d_in, const int* in_sizes, int n_in,
                              void* d_out, int out_size, void* d_ws, size_t ws_size,
                              hipStream_t stream) {
    const float* x = (const float*)d_in[0];   // [N,2] f32
    const float* mu = (const float*)d_in[1];  // [2] f32
    float* out = (float*)d_out;               // [N] f32

    int N = in_sizes[0] / 2;       // 16777216
    int n_pairs = N / 2;           // 8388608 (N even)

    const int block = 256;
    int grid = (n_pairs + block - 1) / block;
    const int max_grid = 2048;     // 256 CUs * 8 blocks, grid-stride the rest
    if (grid > max_grid) grid = max_grid;

    gauss_pdf_kernel<<<grid, block, 0, stream>>>(
        (const f32x4*)x, mu, (f32x2*)out, n_pairs);
}

// Round 4
// 34.955 us; speedup vs baseline: 1.0257x; 1.0257x over previous
//
#include <hip/hip_runtime.h>
#include <hip/hip_bf16.h>

// out[i] = exp(-0.5 * 0.54 * ((x[i,0]-mu0)^2 + (x[i,1]-mu1)^2))
// Memory-bound streaming. 4 rows per lane per iter:
//   2x float4 loads (rows 4i..4i+3), 1x float4 store (outs 4i..4i+3).
// nt hints REVERTED (R3: -5% regression on mixed read+write stream).

__global__ void gauss_pdf_kernel(const float4* __restrict__ x,
                                 const float* __restrict__ mu,
                                 float4* __restrict__ out,
                                 int n_quads) {
    const float m0 = mu[0];
    const float m1 = mu[1];
    const float k = -0.5f * 0.54f;  // -0.27

    int idx = blockIdx.x * blockDim.x + threadIdx.x;
    int stride = gridDim.x * blockDim.x;
    for (int i = idx; i < n_quads; i += stride) {
        float4 a = x[2 * i];      // rows 4i, 4i+1
        float4 b = x[2 * i + 1];  // rows 4i+2, 4i+3
        float d0 = a.x - m0, d1 = a.y - m1;
        float d2 = a.z - m0, d3 = a.w - m1;
        float d4 = b.x - m0, d5 = b.y - m1;
        float d6 = b.z - m0, d7 = b.w - m1;
        float4 r;
        r.x = __expf((d0 * d0 + d1 * d1) * k);
        r.y = __expf((d2 * d2 + d3 * d3) * k);
        r.z = __expf((d4 * d4 + d5 * d5) * k);
        r.w = __expf((d6 * d6 + d7 * d7) * k);
        out[i] = r;
    }
}

extern "C" void kernel_launch(void* const* d_in, const int* in_sizes, int n_in,
                              void* d_out, int out_size, void* d_ws, size_t ws_size,
                              hipStream_t stream) {
    const float* x = (const float*)d_in[0];   // [N,2] f32
    const float* mu = (const float*)d_in[1];  // [2] f32
    float* out = (float*)d_out;               // [N] f32

    int N = in_sizes[0] / 2;       // 16777216
    int n_quads = N / 4;           // 4194304 (N divisible by 4)

    const int block = 256;
    int grid = (n_quads + block - 1) / block;
    const int max_grid = 2048;     // 256 CUs * 8 blocks, grid-stride the rest
    if (grid > max_grid) grid = max_grid;

    gauss_pdf_kernel<<<grid, block, 0, stream>>>(
        (const float4*)x, mu, (float4*)out, n_quads);
}

// Round 5
// 34.269 us; speedup vs baseline: 1.0462x; 1.0200x over previous
//
#include <hip/hip_runtime.h>
#include <hip/hip_bf16.h>

// out[i] = exp(-0.5 * 0.54 * ((x[i,0]-mu0)^2 + (x[i,1]-mu1)^2))
// Memory-bound: 12 B/row traffic. One float4 load = 2 rows (16 B/lane),
// one float2 store = 2 outputs per lane per iteration.
// BEST variant (R1: 34.17 us = 5.89 TB/s, 93.6% of measured copy ceiling).
// Tried and reverted: nt hints (R3, -5%), 4 rows/lane (R4, -2%).

__global__ void gauss_pdf_kernel(const float4* __restrict__ x,
                                 const float* __restrict__ mu,
                                 float2* __restrict__ out,
                                 int n_pairs) {
    const float m0 = mu[0];
    const float m1 = mu[1];
    const float k = -0.5f * 0.54f;  // -0.27

    int idx = blockIdx.x * blockDim.x + threadIdx.x;
    int stride = gridDim.x * blockDim.x;
    for (int i = idx; i < n_pairs; i += stride) {
        float4 v = x[i];  // rows 2i and 2i+1: (x0,y0,x1,y1)
        float d0 = v.x - m0;
        float d1 = v.y - m1;
        float d2 = v.z - m0;
        float d3 = v.w - m1;
        float q0 = (d0 * d0 + d1 * d1) * k;
        float q1 = (d2 * d2 + d3 * d3) * k;
        float2 r;
        r.x = __expf(q0);
        r.y = __expf(q1);
        out[i] = r;
    }
}

extern "C" void kernel_launch(void* const* d_in, const int* in_sizes, int n_in,
                              void* d_out, int out_size, void* d_ws, size_t ws_size,
                              hipStream_t stream) {
    const float* x = (const float*)d_in[0];   // [N,2] f32
    const float* mu = (const float*)d_in[1];  // [2] f32
    float* out = (float*)d_out;               // [N] f32

    int N = in_sizes[0] / 2;       // 16777216
    int n_pairs = N / 2;           // 8388608 (N even)

    const int block = 256;
    int grid = (n_pairs + block - 1) / block;
    const int max_grid = 2048;     // 256 CUs * 8 blocks, grid-stride the rest
    if (grid > max_grid) grid = max_grid;

    gauss_pdf_kernel<<<grid, block, 0, stream>>>(
        (const float4*)x, mu, (float2*)out, n_pairs);
}